// Round 4
// baseline (304.876 us; speedup 1.0000x reference)
//
#include <hip/hip_runtime.h>
#include <cstdint>
#include <cstddef>

// ---------- types ----------
typedef __attribute__((ext_vector_type(8))) short short8;   // 8 bf16 = 4 VGPR
typedef __attribute__((ext_vector_type(4))) float floatx4;  // MFMA C/D

#define NTOK   4096
#define NSLOT  12288     // 2*NTOK routed + NTOK shared
#define SHSLOT 8192      // shared-expert rows start here (exact top-2)
#define MAT_ELEMS (1024 * 1024)

__device__ __forceinline__ unsigned short f2b(float f) {
  unsigned u = __float_as_uint(f);
  u = (u + 0x7fffu + ((u >> 16) & 1u)) >> 16;
  return (unsigned short)u;
}
__device__ __forceinline__ float b2f(unsigned short b) {
  return __uint_as_float((unsigned)b << 16);
}

// async global->LDS, 16B per lane. gsrc: per-lane address, ldst: wave-uniform base.
#define GLD16(gsrc, ldst)                                                              \
  __builtin_amdgcn_global_load_lds(                                                    \
      (const __attribute__((address_space(1))) unsigned int*)(gsrc),                   \
      (__attribute__((address_space(3))) unsigned int*)(ldst), 16, 0, 0)

// counted waitcnt (raw; never let the compiler attach a drain)
#define WAITVM(N) asm volatile("s_waitcnt vmcnt(" #N ")" ::: "memory")

// ---------- K1: fused prep = router (bid<256, dispatched FIRST) + transpose ----
#define T2PITCH 260

__global__ __launch_bounds__(256) void prep_kernel(
    const float* __restrict__ x, const float* __restrict__ Wr,
    const float* __restrict__ loopTable, const int* __restrict__ loopIdx,
    const float* __restrict__ Wg, const float* __restrict__ Wu,
    const float* __restrict__ Wd, const float* __restrict__ sg,
    const float* __restrict__ su, const float* __restrict__ sd,
    unsigned short* __restrict__ Xb, int* __restrict__ cnt,
    int* __restrict__ permSparse, float* __restrict__ wSparse,
    int2* __restrict__ tokenEPos, unsigned short* __restrict__ Wt) {
  __shared__ __align__(16) char shraw[128 * T2PITCH];
  float (*red)[16][8] = (float(*)[16][8])shraw;          // router: [4][16][8]
  float (*sbias)[8] = (float(*)[8])(shraw + 2048);       // [4][8]
  int* lcnt = (int*)(shraw + 2048 + 128);                // [8]
  int* lbase = (int*)(shraw + 2048 + 160);               // [8]

  int tid = threadIdx.x;
  int bid = blockIdx.x;

  if (bid >= 256) {
    // ---------------- transpose role ----------------
    int tt = bid - 256;               // 0..1727
    int m = tt >> 6;                  // 0..26
    int tl = tt & 63;
    int k0 = (tl >> 3) << 7;          // 8 k-tiles of 128
    int n0 = (tl & 7) << 7;           // 8 n-tiles of 128
    int type = m / 9, e = m % 9;
    const float* src;
    if (type == 0)      src = (e < 8) ? Wg + (size_t)e * MAT_ELEMS : sg;
    else if (type == 1) src = (e < 8) ? Wu + (size_t)e * MAT_ELEMS : su;
    else                src = (e < 8) ? Wd + (size_t)e * MAT_ELEMS : sd;

    int rsub = tid >> 5;              // 0..7
    int nl4 = (tid & 31) << 2;        // float4 col
    const float* srcb = src + (size_t)k0 * 1024 + n0;
#pragma unroll
    for (int j = 0; j < 16; ++j) {
      int r = (j << 3) + rsub;        // k-row 0..127
      float4 v = *(const float4*)(srcb + (size_t)r * 1024 + nl4);
      char* p0 = shraw + (size_t)(nl4 + 0) * T2PITCH + (r << 1);
      *(unsigned short*)(p0)               = f2b(v.x);
      *(unsigned short*)(p0 + T2PITCH)     = f2b(v.y);
      *(unsigned short*)(p0 + 2 * T2PITCH) = f2b(v.z);
      *(unsigned short*)(p0 + 3 * T2PITCH) = f2b(v.w);
    }
    __syncthreads();

    int nrow = tid >> 4;              // 0..15
    int l16 = tid & 15;               // k-chunk of 8 bf16
    unsigned short* dstm = Wt + (size_t)m * MAT_ELEMS;
#pragma unroll
    for (int p = 0; p < 8; ++p) {
      int n = (p << 4) + nrow;        // 0..127
      const char* rb = shraw + (size_t)n * T2PITCH + (l16 << 4);
      uint4 o;
      o.x = *(const unsigned*)(rb + 0);
      o.y = *(const unsigned*)(rb + 4);
      o.z = *(const unsigned*)(rb + 8);
      o.w = *(const unsigned*)(rb + 12);
      *(uint4*)&dstm[(size_t)(n0 + n) * 1024 + k0 + (l16 << 3)] = o;
    }
    return;
  }

  // ---------------- router role (bid 0..255: dispatched first) -------
  int lane = tid & 63;
  int seg = __builtin_amdgcn_readfirstlane(tid >> 6);
  int tok0 = bid << 4;
  int t16 = lane >> 2;
  int part = lane & 3;
  int tok = tok0 + t16;

  if (tid < 8) lcnt[tid] = 0;

  float bp[8] = {0, 0, 0, 0, 0, 0, 0, 0};
  {
    const float* emb = loopTable + (size_t)(*loopIdx) * 1024;
    int d = seg * 256 + lane * 4;
    float4 ev = *(const float4*)(emb + d);
    float es[4] = {ev.x, ev.y, ev.z, ev.w};
#pragma unroll
    for (int r = 0; r < 4; r++) {
      const float4* w4 = (const float4*)(Wr + (size_t)(1024 + d + r) * 8);
      float4 wa = w4[0], wb = w4[1];
      float e1 = es[r];
      bp[0] += e1 * wa.x; bp[1] += e1 * wa.y; bp[2] += e1 * wa.z; bp[3] += e1 * wa.w;
      bp[4] += e1 * wb.x; bp[5] += e1 * wb.y; bp[6] += e1 * wb.z; bp[7] += e1 * wb.w;
    }
  }
#pragma unroll
  for (int off = 32; off > 0; off >>= 1)
#pragma unroll
    for (int e = 0; e < 8; e++) bp[e] += __shfl_xor(bp[e], off, 64);
  if (lane == 0)
#pragma unroll
    for (int e = 0; e < 8; e++) sbias[seg][e] = bp[e];

  float lg[8] = {0, 0, 0, 0, 0, 0, 0, 0};
  const float* xr = x + (size_t)tok * 1024 + seg * 256 + part * 64;
  const float* wrb = Wr + (size_t)(seg * 256 + part * 64) * 8;
  for (int i = 0; i < 64; i += 4) {
    float4 xv = *(const float4*)(xr + i);
    float xs[4] = {xv.x, xv.y, xv.z, xv.w};
#pragma unroll
    for (int r = 0; r < 4; r++) {
      const float4* w4 = (const float4*)(wrb + (size_t)(i + r) * 8);
      float4 wa = w4[0], wb = w4[1];
      float xv1 = xs[r];
      lg[0] += xv1 * wa.x; lg[1] += xv1 * wa.y; lg[2] += xv1 * wa.z; lg[3] += xv1 * wa.w;
      lg[4] += xv1 * wb.x; lg[5] += xv1 * wb.y; lg[6] += xv1 * wb.z; lg[7] += xv1 * wb.w;
    }
  }
#pragma unroll
  for (int off = 1; off < 4; off <<= 1)
#pragma unroll
    for (int e = 0; e < 8; e++) lg[e] += __shfl_xor(lg[e], off, 64);
  if (part == 0)
#pragma unroll
    for (int e = 0; e < 8; e++) red[seg][t16][e] = lg[e];
  __syncthreads();

  int i0s = 0, i1s = 0, pos0s = 0, pos1s = 0;
  float p0s = 0.f, p1s = 0.f;
  if (tid < 16) {
    float l[8];
#pragma unroll
    for (int e = 0; e < 8; e++)
      l[e] = red[0][tid][e] + red[1][tid][e] + red[2][tid][e] + red[3][tid][e] +
             sbias[0][e] + sbias[1][e] + sbias[2][e] + sbias[3][e];
    int i0 = 0; float l0 = l[0];
#pragma unroll
    for (int e = 1; e < 8; e++) if (l[e] > l0) { l0 = l[e]; i0 = e; }
    int i1 = -1; float l1 = -1e30f;
#pragma unroll
    for (int e = 0; e < 8; e++) if (e != i0 && l[e] > l1) { l1 = l[e]; i1 = e; }
    i0s = i0; i1s = i1;
    p0s = 1.0f / (1.0f + __expf(-l0));
    p1s = 1.0f / (1.0f + __expf(-l1));
    pos0s = atomicAdd(&lcnt[i0], 1);
    pos1s = atomicAdd(&lcnt[i1], 1);
  }
  __syncthreads();
  if (tid < 8) lbase[tid] = atomicAdd(&cnt[tid], lcnt[tid]);
  __syncthreads();
  if (tid < 16) {
    int tk = tok0 + tid;
    int pos0 = lbase[i0s] + pos0s;
    int pos1 = lbase[i1s] + pos1s;
    permSparse[i0s * NTOK + pos0] = tk; wSparse[i0s * NTOK + pos0] = p0s;
    permSparse[i1s * NTOK + pos1] = tk; wSparse[i1s * NTOK + pos1] = p1s;
    tokenEPos[tk * 2 + 0] = make_int2(i0s, pos0);
    tokenEPos[tk * 2 + 1] = make_int2(i1s, pos1);
  }

  const float4* xs4 = (const float4*)(x + (size_t)tok0 * 1024);
  uint2* dst = (uint2*)(Xb + (size_t)tok0 * 1024);
  for (int i = tid; i < 16 * 256; i += 256) {
    float4 v = xs4[i];
    uint2 pk;
    pk.x = (unsigned)f2b(v.x) | ((unsigned)f2b(v.y) << 16);
    pk.y = (unsigned)f2b(v.z) | ((unsigned)f2b(v.w) << 16);
    dst[i] = pk;
  }
}

__device__ __forceinline__ void expert_range(const int* __restrict__ cnt, int e,
                                             int& c, int& off) {
  if (e == 8) { c = NTOK; off = SHSLOT; return; }
  off = 0; c = 0;
#pragma unroll
  for (int i = 0; i < 8; i++) {
    int cv = cnt[i];
    if (i < e) off += cv;
    if (i == e) c = cv;
  }
}

// ---------- K3: gate+up GEMM, 3-slot k-half rotation, counted vmcnt ----------
// Half h (k in [32h,32h+32)) lives in slot h%3. Region h: barrier; stage h+2;
// vmcnt(12) certifies half h WITHOUT draining; barrier; ds_read+MFMA (setprio).
// LDS physical layout: row-pair interleave slot=((r&1)*4+c)^((r>>1)&7) applied
// to BOTH the pre-swizzled global source and the frag reads (GLD16 dest linear,
// G21-compliant). Frag reads hit all 8 slots of each 128B group once: 0 conflicts.
__global__ __launch_bounds__(256, 2) void gateup_gemm(
    const unsigned short* __restrict__ Xb, const unsigned short* __restrict__ Wt,
    const int* __restrict__ cnt, const int* __restrict__ permSparse,
    const float* __restrict__ wSparse, unsigned short* __restrict__ Hbuf) {
  int e = blockIdx.z;
  int c, off;
  expert_range(cnt, e, c, off);
  int m0 = blockIdx.y << 7;
  if (m0 >= c) return;
  int row_base = off + m0;
  int valid_m = c - m0; if (valid_m > 128) valid_m = 128;
  int n0 = blockIdx.x << 7;

  __shared__ __align__(16) char lds[3 * 24576];   // 72KB: 3 slots x {A,G,U 8KB}

  int tid = threadIdx.x;
  int wv = tid >> 6, lane = tid & 63;
  int wm = wv >> 1, wn = wv & 1;

  const unsigned short* Gg = Wt + (size_t)e * MAT_ELEMS + (size_t)n0 * 1024;
  const unsigned short* Ug = Wt + (size_t)(9 + e) * MAT_ELEMS + (size_t)n0 * 1024;

  // staging lane geometry (pre-swizzled global source)
  int g = lane >> 3, s8 = lane & 7, v = s8 ^ g;
  int vr = v >> 2;                 // row parity
  int c8 = (v & 3) << 3;           // k-element offset within 32-half
  int rl[2]; rl[0] = (wv << 5) + (g << 1) + vr; rl[1] = rl[0] + 16;

  const unsigned short* gA[2];
#pragma unroll
  for (int i = 0; i < 2; ++i) {
    int r = m0 + rl[i];
    int tok;
    if (e < 8) tok = (r < c) ? permSparse[e * NTOK + r] : 0;
    else       tok = (r < c) ? r : 0;
    gA[i] = Xb + (size_t)tok * 1024;
  }
  const unsigned short* gG[2] = { Gg + (size_t)rl[0] * 1024, Gg + (size_t)rl[1] * 1024 };
  const unsigned short* gU[2] = { Ug + (size_t)rl[0] * 1024, Ug + (size_t)rl[1] * 1024 };
  int ib[2] = { (wv << 11), (wv << 11) + 1024 };   // wave-uniform LDS instr bases

  // frag-read offsets (swizzled)
  int q = lane >> 4;
  int offA[4], offB[4];
#pragma unroll
  for (int i = 0; i < 4; ++i) {
    int rA = (wm << 6) + (lane & 15) + (i << 4);
    offA[i] = ((rA >> 1) << 7) + (((((rA & 1) << 2) + q) ^ ((rA >> 1) & 7)) << 4);
    int rB = (wn << 6) + (lane & 15) + (i << 4);
    offB[i] = ((rB >> 1) << 7) + (((((rB & 1) << 2) + q) ^ ((rB >> 1) & 7)) << 4);
  }

  floatx4 accG[4][4], accU[4][4];
#pragma unroll
  for (int i = 0; i < 4; i++)
#pragma unroll
    for (int j = 0; j < 4; j++) {
      accG[i][j] = floatx4{0.f, 0.f, 0.f, 0.f};
      accU[i][j] = floatx4{0.f, 0.f, 0.f, 0.f};
    }

#define GU_STAGE(SB, H) do { int ke = ((H) << 5) + c8;                     \
    GLD16(gA[0] + ke, lds + (SB) + ib[0]);                                 \
    GLD16(gA[1] + ke, lds + (SB) + ib[1]);                                 \
    GLD16(gG[0] + ke, lds + (SB) + 8192 + ib[0]);                          \
    GLD16(gG[1] + ke, lds + (SB) + 8192 + ib[1]);                          \
    GLD16(gU[0] + ke, lds + (SB) + 16384 + ib[0]);                         \
    GLD16(gU[1] + ke, lds + (SB) + 16384 + ib[1]); } while (0)

  int sb0 = 0, sb1 = 24576, sb2 = 49152;
  GU_STAGE(sb0, 0);
  GU_STAGE(sb1, 1);

  for (int h = 0; h < 32; ++h) {
    __builtin_amdgcn_s_barrier();            // slot sb2's readers (region h-1) done
    __builtin_amdgcn_sched_barrier(0);
    if (h < 30) GU_STAGE(sb2, h + 2);
    if (h < 30)       WAITVM(12);            // certify half h; h+1,h+2 stay in flight
    else if (h == 30) WAITVM(6);
    else              WAITVM(0);
    __builtin_amdgcn_s_barrier();            // all waves certified slot sb0
    __builtin_amdgcn_sched_barrier(0);
    short8 af[4];
#pragma unroll
    for (int mi = 0; mi < 4; ++mi)
      af[mi] = *(const short8*)(lds + sb0 + offA[mi]);
    __builtin_amdgcn_s_setprio(1);
#pragma unroll
    for (int ni = 0; ni < 4; ++ni) {
      short8 gf = *(const short8*)(lds + sb0 + 8192 + offB[ni]);
      short8 uf = *(const short8*)(lds + sb0 + 16384 + offB[ni]);
#pragma unroll
      for (int mi = 0; mi < 4; ++mi) {
        accG[mi][ni] = __builtin_amdgcn_mfma_f32_16x16x32_bf16(af[mi], gf, accG[mi][ni], 0, 0, 0);
        accU[mi][ni] = __builtin_amdgcn_mfma_f32_16x16x32_bf16(af[mi], uf, accU[mi][ni], 0, 0, 0);
      }
    }
    __builtin_amdgcn_s_setprio(0);
    int t = sb0; sb0 = sb1; sb1 = sb2; sb2 = t;
  }
#undef GU_STAGE

  int colLane = lane & 15, quad = lane >> 4;
#pragma unroll
  for (int mi = 0; mi < 4; mi++) {
#pragma unroll
    for (int reg = 0; reg < 4; reg++) {
      int mrow = (wm << 6) + (mi << 4) + (quad << 2) + reg;
      if (mrow < valid_m) {
        int r = m0 + mrow;
        float w = (e < 8) ? wSparse[e * NTOK + r] : 1.0f;
        unsigned short* hr = Hbuf + (size_t)(row_base + mrow) * 1024 + n0 + (wn << 6) + colLane;
#pragma unroll
        for (int ni = 0; ni < 4; ni++) {
          float gg2 = accG[mi][ni][reg];
          float u = accU[mi][ni][reg];
          float hh = (gg2 / (1.0f + __expf(-gg2))) * u * w;
          hr[ni << 4] = f2b(hh);
        }
      }
    }
  }
}

// ---------- K4: down GEMM, same 3-slot rotation ----------
__global__ __launch_bounds__(256, 2) void down_gemm(
    const unsigned short* __restrict__ Hbuf, const unsigned short* __restrict__ Wt,
    const int* __restrict__ cnt, unsigned short* __restrict__ Dbuf) {
  int e = blockIdx.z;
  int c, off;
  expert_range(cnt, e, c, off);
  int m0 = blockIdx.y << 7;
  if (m0 >= c) return;
  int row_base = off + m0;
  int valid_m = c - m0; if (valid_m > 128) valid_m = 128;
  int n0 = blockIdx.x << 7;

  __shared__ __align__(16) char lds[3 * 16384];   // 48KB: 3 slots x {A,B 8KB}

  int tid = threadIdx.x;
  int wv = tid >> 6, lane = tid & 63;
  int wm = wv >> 1, wn = wv & 1;

  const unsigned short* Ag = Hbuf + (size_t)row_base * 1024;
  const unsigned short* Bg = Wt + (size_t)(18 + e) * MAT_ELEMS + (size_t)n0 * 1024;

  int g = lane >> 3, s8 = lane & 7, v = s8 ^ g;
  int vr = v >> 2;
  int c8 = (v & 3) << 3;
  int rl[2]; rl[0] = (wv << 5) + (g << 1) + vr; rl[1] = rl[0] + 16;

  const unsigned short* gA[2] = { Ag + (size_t)rl[0] * 1024, Ag + (size_t)rl[1] * 1024 };
  const unsigned short* gB[2] = { Bg + (size_t)rl[0] * 1024, Bg + (size_t)rl[1] * 1024 };
  int ib[2] = { (wv << 11), (wv << 11) + 1024 };

  int q = lane >> 4;
  int offA[4], offB[4];
#pragma unroll
  for (int i = 0; i < 4; ++i) {
    int rA = (wm << 6) + (lane & 15) + (i << 4);
    offA[i] = ((rA >> 1) << 7) + (((((rA & 1) << 2) + q) ^ ((rA >> 1) & 7)) << 4);
    int rB = (wn << 6) + (lane & 15) + (i << 4);
    offB[i] = ((rB >> 1) << 7) + (((((rB & 1) << 2) + q) ^ ((rB >> 1) & 7)) << 4);
  }

  floatx4 acc[4][4];
#pragma unroll
  for (int i = 0; i < 4; i++)
#pragma unroll
    for (int j = 0; j < 4; j++) acc[i][j] = floatx4{0.f, 0.f, 0.f, 0.f};

#define DN_STAGE(SB, H) do { int ke = ((H) << 5) + c8;                     \
    GLD16(gA[0] + ke, lds + (SB) + ib[0]);                                 \
    GLD16(gA[1] + ke, lds + (SB) + ib[1]);                                 \
    GLD16(gB[0] + ke, lds + (SB) + 8192 + ib[0]);                          \
    GLD16(gB[1] + ke, lds + (SB) + 8192 + ib[1]); } while (0)

  int sb0 = 0, sb1 = 16384, sb2 = 32768;
  DN_STAGE(sb0, 0);
  DN_STAGE(sb1, 1);

  for (int h = 0; h < 32; ++h) {
    __builtin_amdgcn_s_barrier();
    __builtin_amdgcn_sched_barrier(0);
    if (h < 30) DN_STAGE(sb2, h + 2);
    if (h < 30)       WAITVM(8);
    else if (h == 30) WAITVM(4);
    else              WAITVM(0);
    __builtin_amdgcn_s_barrier();
    __builtin_amdgcn_sched_barrier(0);
    short8 af[4];
#pragma unroll
    for (int mi = 0; mi < 4; ++mi)
      af[mi] = *(const short8*)(lds + sb0 + offA[mi]);
    __builtin_amdgcn_s_setprio(1);
#pragma unroll
    for (int ni = 0; ni < 4; ++ni) {
      short8 bf = *(const short8*)(lds + sb0 + 8192 + offB[ni]);
#pragma unroll
      for (int mi = 0; mi < 4; ++mi)
        acc[mi][ni] = __builtin_amdgcn_mfma_f32_16x16x32_bf16(af[mi], bf, acc[mi][ni], 0, 0, 0);
    }
    __builtin_amdgcn_s_setprio(0);
    int t = sb0; sb0 = sb1; sb1 = sb2; sb2 = t;
  }
#undef DN_STAGE

  int colLane = lane & 15, quad = lane >> 4;
#pragma unroll
  for (int mi = 0; mi < 4; mi++) {
#pragma unroll
    for (int reg = 0; reg < 4; reg++) {
      int mrow = (wm << 6) + (mi << 4) + (quad << 2) + reg;
      if (mrow < valid_m) {
        unsigned short* dr = Dbuf + (size_t)(row_base + mrow) * 1024 + n0 + (wn << 6) + colLane;
#pragma unroll
        for (int ni = 0; ni < 4; ni++)
          dr[ni << 4] = f2b(acc[mi][ni][reg]);
      }
    }
  }
}

// ---------- K5: combine shared + 2 routed rows -> out (fp32) ----------
__global__ __launch_bounds__(256) void combine_kernel(
    const unsigned short* __restrict__ Dbuf, const int* __restrict__ cnt,
    const int2* __restrict__ tokenEPos, float* __restrict__ out) {
  __shared__ int soffs[8];
  if (threadIdx.x == 0) {
    int s = 0;
    for (int i = 0; i < 8; i++) { soffs[i] = s; s += cnt[i]; }
  }
  __syncthreads();
  int tok = (blockIdx.x << 1) + (threadIdx.x >> 7);
  int lane = threadIdx.x & 127;
  int2 a = tokenEPos[tok * 2 + 0];
  int2 b = tokenEPos[tok * 2 + 1];
  int s0 = soffs[a.x] + a.y;
  int s1 = soffs[b.x] + b.y;
  int ssh = SHSLOT + tok;
  int d = lane << 3;
  uint4 r0 = *(const uint4*)(Dbuf + (size_t)ssh * 1024 + d);
  uint4 r1 = *(const uint4*)(Dbuf + (size_t)s0 * 1024 + d);
  uint4 r2 = *(const uint4*)(Dbuf + (size_t)s1 * 1024 + d);
  float o[8];
  const unsigned* u0 = (const unsigned*)&r0;
  const unsigned* u1 = (const unsigned*)&r1;
  const unsigned* u2 = (const unsigned*)&r2;
#pragma unroll
  for (int i = 0; i < 4; i++) {
    o[2 * i + 0] = b2f((unsigned short)(u0[i] & 0xffff)) +
                   b2f((unsigned short)(u1[i] & 0xffff)) +
                   b2f((unsigned short)(u2[i] & 0xffff));
    o[2 * i + 1] = b2f((unsigned short)(u0[i] >> 16)) +
                   b2f((unsigned short)(u1[i] >> 16)) +
                   b2f((unsigned short)(u2[i] >> 16));
  }
  float* orow = out + (size_t)tok * 1024 + d;
  *(float4*)(orow + 0) = make_float4(o[0], o[1], o[2], o[3]);
  *(float4*)(orow + 4) = make_float4(o[4], o[5], o[6], o[7]);
}

// ---------- launch ----------
extern "C" void kernel_launch(void* const* d_in, const int* in_sizes, int n_in,
                              void* d_out, int out_size, void* d_ws, size_t ws_size,
                              hipStream_t stream) {
  const float* x  = (const float*)d_in[0];
  const float* sg = (const float*)d_in[1];
  const float* su = (const float*)d_in[2];
  const float* sd = (const float*)d_in[3];
  const float* Wg = (const float*)d_in[4];
  const float* Wu = (const float*)d_in[5];
  const float* Wd = (const float*)d_in[6];
  const float* Wr = (const float*)d_in[7];
  const float* loopTable = (const float*)d_in[8];
  const int*   loopIdx   = (const int*)d_in[9];
  float* out = (float*)d_out;

  char* w = (char*)d_ws;
  unsigned short* Wt = (unsigned short*)w;    w += (size_t)27 * MAT_ELEMS * 2;
  unsigned short* Xb = (unsigned short*)w;    w += (size_t)NTOK * 1024 * 2;
  unsigned short* Hbuf = (unsigned short*)w;  w += (size_t)NSLOT * 1024 * 2;
  unsigned short* Dbuf = (unsigned short*)w;  w += (size_t)NSLOT * 1024 * 2;
  int*   cnt        = (int*)w;   w += 16 * 4;
  int*   permSparse = (int*)w;   w += (size_t)8 * NTOK * 4;
  float* wSparse    = (float*)w; w += (size_t)8 * NTOK * 4;
  int2*  tokenEPos  = (int2*)w;  w += (size_t)NTOK * 2 * 8;

  hipMemsetAsync(cnt, 0, 32, stream);
  prep_kernel<<<256 + 27 * 64, 256, 0, stream>>>(
      x, Wr, loopTable, loopIdx, Wg, Wu, Wd, sg, su, sd,
      Xb, cnt, permSparse, wSparse, tokenEPos, Wt);
  gateup_gemm<<<dim3(8, 32, 9), 256, 0, stream>>>(Xb, Wt, cnt, permSparse,
                                                  wSparse, Hbuf);
  down_gemm<<<dim3(8, 32, 9), 256, 0, stream>>>(Hbuf, Wt, cnt, Dbuf);
  combine_kernel<<<2048, 256, 0, stream>>>(Dbuf, cnt, tokenEPos, out);
}